// Round 10
// baseline (484.656 us; speedup 1.0000x reference)
//
#include <hip/hip_runtime.h>
#include <hip/hip_bf16.h>
#include <cstdint>
#include <cstddef>

typedef unsigned short u16;
typedef __attribute__((ext_vector_type(8))) __bf16 bf16x8;
typedef __attribute__((ext_vector_type(4))) float f32x4;

#define AS1 __attribute__((address_space(1)))
#define AS3 __attribute__((address_space(3)))

__device__ __forceinline__ u16 f2bf(float f) {
    union { float f; uint32_t u; } v; v.f = f;
    uint32_t r = (v.u + 0x7FFFu + ((v.u >> 16) & 1u)) >> 16;
    return (u16)r;
}

__device__ __forceinline__ float bf2f(u16 b) {
    union { uint32_t u; float f; } v; v.u = ((uint32_t)b) << 16;
    return v.f;
}

__device__ __forceinline__ uint32_t pack_bf2(float lo, float hi) {
    __hip_bfloat162 p = __float22bfloat162_rn(float2{lo, hi});
    union { __hip_bfloat162 b; uint32_t u; } v; v.b = p;
    return v.u;
}

__device__ __forceinline__ f32x4 mfma16(bf16x8 a, bf16x8 b, f32x4 c) {
    return __builtin_amdgcn_mfma_f32_16x16x32_bf16(a, b, c, 0, 0, 0);
}

// async global->LDS, 16B per lane; lane i lands at base + i*16.
__device__ __forceinline__ void async16(const u16* g, u16* lds_uniform_base) {
    __builtin_amdgcn_global_load_lds((const AS1 void*)g, (AS3 void*)lds_uniform_base, 16, 0, 0);
}

// XCD-aware block remap for ATTENTION ONLY (requires nwg % 8 == 0).
// Round-7 measurement: natural round-robin already partitions GEMM bx per
// XCD; chunked remap there cost ~30us. Attention's shared K/V is indexed by
// the SLOW coord -> chunked remap wins (FETCH 108->22MB).
__device__ __forceinline__ int xcd_swz(int nwg) {
    int b = blockIdx.x + gridDim.x * (blockIdx.y + gridDim.y * blockIdx.z);
    return (b & 7) * (nwg >> 3) + (b >> 3);
}

// ------------------------------------------------------------ fused prep
__global__ __launch_bounds__(256)
void k_prep(const float* __restrict__ x, u16* __restrict__ xb,
            const float* __restrict__ wq, const float* __restrict__ wk,
            const float* __restrict__ wv, const float* __restrict__ wo,
            const float* __restrict__ w1, const float* __restrict__ w2,
            u16* __restrict__ wqkvt, u16* __restrict__ wot,
            u16* __restrict__ w1t, u16* __restrict__ w2t)
{
    int bx = blockIdx.x;
    if (bx < 6144) {
        int i = (bx * 256 + threadIdx.x) * 4;
        float4 f = *(const float4*)(x + i);
        xb[i + 0] = f2bf(f.x); xb[i + 1] = f2bf(f.y);
        xb[i + 2] = f2bf(f.z); xb[i + 3] = f2bf(f.w);
        return;
    }
    int t = bx - 6144;
    const float* in; u16* out; int R, C;
    if (t < 2304) {
        int m = t / 576; t -= m * 576;
        R = 768; C = 768;
        in = (m == 0) ? wq : (m == 1) ? wk : (m == 2) ? wv : wo;
        out = (m < 3) ? wqkvt + (size_t)m * 768 * 768 : wot;
    } else if (t < 4608) {
        t -= 2304; in = w1; out = w1t; R = 768; C = 3072;
    } else {
        t -= 4608; in = w2; out = w2t; R = 3072; C = 768;
    }
    int tilesX = C >> 5;
    int c0 = (t % tilesX) * 32, r0 = (t / tilesX) * 32;
    __shared__ float tile[32][33];
    int tx = threadIdx.x & 31, ty = threadIdx.x >> 5;
    #pragma unroll
    for (int i = ty; i < 32; i += 8)
        tile[i][tx] = in[(size_t)(r0 + i) * C + c0 + tx];
    __syncthreads();
    #pragma unroll
    for (int i = ty; i < 32; i += 8)
        out[(size_t)(c0 + i) * R + r0 + tx] = f2bf(tile[tx][i]);
}

// ------------------------------------------------------------ 256x256 GEMM
// The 128^2 tile was operand-refetch-BW-bound (65 FLOP/B; FF1 fetched 590MB
// for 38.7 GFLOP -> ~94us HBM floor; pipelining tweaks were neutral, rounds
// 8/9). 256^2 tile doubles arithmetic intensity (131 FLOP/B) and halves
// fetch. 512 thr = 8 waves (2M x 4N), each wave owns 128x64 (acc[8][4]).
// Triple-buffered 96KB LDS, depth-2 prefetch, counted vmcnt + raw barrier
// (proven loop from round 9; each wave still issues 4 loads/tile).
template <bool RELU>
__global__ __launch_bounds__(512, 2)
void k_gemm256(const u16* __restrict__ A, const u16* __restrict__ Bt,
               const float* __restrict__ bias, u16* __restrict__ Cb,
               int M, int N, int K)
{
    __shared__ __align__(16) u16 lA[3 * 8192];
    __shared__ __align__(16) u16 lB[3 * 8192];
    const int tid = threadIdx.x;
    const int w = tid >> 6, lane = tid & 63;
    const int quad = lane >> 4, l15 = lane & 15;
    const int m0 = blockIdx.x * 256, n0 = blockIdx.y * 256;
    const int wm = (w >> 2) * 128, wn = (w & 3) * 64;
    const int sw = (quad ^ ((l15 >> 1) & 3)) * 8;
    const int dst = w * 512;   // wave-uniform LDS chunk base (u16)

    const u16* pA[2]; const u16* pB[2];
    #pragma unroll
    for (int r = 0; r < 2; ++r) {
        int c = r * 512 + tid;
        int row = c >> 2, ch = (c & 3) ^ ((row >> 1) & 3);
        pA[r] = A + (size_t)(m0 + row) * K + ch * 8;
        pB[r] = Bt + (size_t)(n0 + row) * K + ch * 8;
    }

    const f32x4 fz = {0.f, 0.f, 0.f, 0.f};
    f32x4 acc[8][4];
    #pragma unroll
    for (int i = 0; i < 8; ++i)
        #pragma unroll
        for (int j = 0; j < 4; ++j) acc[i][j] = fz;

    // prologue: issue tiles 0 and 1
    #pragma unroll
    for (int p = 0; p < 2; ++p) {
        #pragma unroll
        for (int r = 0; r < 2; ++r) {
            async16(pA[r], lA + p * 8192 + r * 4096 + dst);
            async16(pB[r], lB + p * 8192 + r * 4096 + dst);
            pA[r] += 32; pB[r] += 32;
        }
    }

    const int nIt = K >> 5;
    int cur = 0;
    for (int it = 0; it < nIt; ++it) {
        if (it + 1 < nIt) asm volatile("s_waitcnt vmcnt(4)" ::: "memory");
        else              asm volatile("s_waitcnt vmcnt(0)" ::: "memory");
        __builtin_amdgcn_s_barrier();
        asm volatile("" ::: "memory");
        if (it + 2 < nIt) {
            int nb = cur + 2; if (nb >= 3) nb -= 3;
            #pragma unroll
            for (int r = 0; r < 2; ++r) {
                async16(pA[r], lA + nb * 8192 + r * 4096 + dst);
                async16(pB[r], lB + nb * 8192 + r * 4096 + dst);
                pA[r] += 32; pB[r] += 32;
            }
        }
        const u16* bA = lA + cur * 8192;
        const u16* bB = lB + cur * 8192;
        bf16x8 af[8], bfr[4];
        #pragma unroll
        for (int i = 0; i < 8; ++i)
            af[i] = *(const bf16x8*)&bA[(wm + i * 16 + l15) * 32 + sw];
        #pragma unroll
        for (int j = 0; j < 4; ++j)
            bfr[j] = *(const bf16x8*)&bB[(wn + j * 16 + l15) * 32 + sw];
        #pragma unroll
        for (int i = 0; i < 8; ++i)
            #pragma unroll
            for (int j = 0; j < 4; ++j)
                acc[i][j] = mfma16(af[i], bfr[j], acc[i][j]);
        asm volatile("" ::: "memory");
        cur = (cur + 1 == 3) ? 0 : cur + 1;
    }
    #pragma unroll
    for (int j = 0; j < 4; ++j) {
        int col = n0 + wn + j * 16 + l15;
        float bv = bias[col];
        #pragma unroll
        for (int i = 0; i < 8; ++i) {
            int row = m0 + wm + i * 16 + quad * 4;
            #pragma unroll
            for (int r = 0; r < 4; ++r) {
                float t = acc[i][j][r] + bv;
                if (RELU) t = fmaxf(t, 0.f);
                Cb[(size_t)(row + r) * N + col] = f2bf(t);
            }
        }
    }
}

// --------------------------------------- 256x256 split-K partial GEMM
__global__ __launch_bounds__(512, 2)
void k_gemm_part256(const u16* __restrict__ A, const u16* __restrict__ Bt,
                    float* __restrict__ C0, float* __restrict__ C1,
                    int M, int N, int K, int Kh)
{
    __shared__ __align__(16) u16 lA[3 * 8192];
    __shared__ __align__(16) u16 lB[3 * 8192];
    const int tid = threadIdx.x;
    const int w = tid >> 6, lane = tid & 63;
    const int quad = lane >> 4, l15 = lane & 15;
    const int m0 = blockIdx.x * 256, n0 = blockIdx.y * 256;
    const int wm = (w >> 2) * 128, wn = (w & 3) * 64;
    const int sw = (quad ^ ((l15 >> 1) & 3)) * 8;
    const int kbeg = blockIdx.z * Kh;
    float* __restrict__ C = blockIdx.z ? C1 : C0;
    const int dst = w * 512;

    const u16* pA[2]; const u16* pB[2];
    #pragma unroll
    for (int r = 0; r < 2; ++r) {
        int c = r * 512 + tid;
        int row = c >> 2, ch = (c & 3) ^ ((row >> 1) & 3);
        pA[r] = A + (size_t)(m0 + row) * K + kbeg + ch * 8;
        pB[r] = Bt + (size_t)(n0 + row) * K + kbeg + ch * 8;
    }

    const f32x4 fz = {0.f, 0.f, 0.f, 0.f};
    f32x4 acc[8][4];
    #pragma unroll
    for (int i = 0; i < 8; ++i)
        #pragma unroll
        for (int j = 0; j < 4; ++j) acc[i][j] = fz;

    #pragma unroll
    for (int p = 0; p < 2; ++p) {
        #pragma unroll
        for (int r = 0; r < 2; ++r) {
            async16(pA[r], lA + p * 8192 + r * 4096 + dst);
            async16(pB[r], lB + p * 8192 + r * 4096 + dst);
            pA[r] += 32; pB[r] += 32;
        }
    }

    const int nIt = Kh >> 5;
    int cur = 0;
    for (int it = 0; it < nIt; ++it) {
        if (it + 1 < nIt) asm volatile("s_waitcnt vmcnt(4)" ::: "memory");
        else              asm volatile("s_waitcnt vmcnt(0)" ::: "memory");
        __builtin_amdgcn_s_barrier();
        asm volatile("" ::: "memory");
        if (it + 2 < nIt) {
            int nb = cur + 2; if (nb >= 3) nb -= 3;
            #pragma unroll
            for (int r = 0; r < 2; ++r) {
                async16(pA[r], lA + nb * 8192 + r * 4096 + dst);
                async16(pB[r], lB + nb * 8192 + r * 4096 + dst);
                pA[r] += 32; pB[r] += 32;
            }
        }
        const u16* bA = lA + cur * 8192;
        const u16* bB = lB + cur * 8192;
        bf16x8 af[8], bfr[4];
        #pragma unroll
        for (int i = 0; i < 8; ++i)
            af[i] = *(const bf16x8*)&bA[(wm + i * 16 + l15) * 32 + sw];
        #pragma unroll
        for (int j = 0; j < 4; ++j)
            bfr[j] = *(const bf16x8*)&bB[(wn + j * 16 + l15) * 32 + sw];
        #pragma unroll
        for (int i = 0; i < 8; ++i)
            #pragma unroll
            for (int j = 0; j < 4; ++j)
                acc[i][j] = mfma16(af[i], bfr[j], acc[i][j]);
        asm volatile("" ::: "memory");
        cur = (cur + 1 == 3) ? 0 : cur + 1;
    }
    #pragma unroll
    for (int j = 0; j < 4; ++j) {
        int col = n0 + wn + j * 16 + l15;
        #pragma unroll
        for (int i = 0; i < 8; ++i) {
            int row = m0 + wm + i * 16 + quad * 4;
            #pragma unroll
            for (int r = 0; r < 4; ++r)
                C[(size_t)(row + r) * N + col] = acc[i][j][r];
        }
    }
}

// ------------------------------------------------------ fused QKV GEMM
// sel==2 (V): output written TRANSPOSED to vtg[D][M] via per-wave LDS
// transpose -> 16B contiguous global stores. Triple-buffered staging in
// qsm[0..24576); V-transpose (after trailing full __syncthreads) aliases
// the staging area. (Kept at 128^2: V-transpose epilogue is wave-64x64.)
__global__ __launch_bounds__(256)
void k_gemm_qkv(const u16* __restrict__ A, const u16* __restrict__ Bt,
                const float* __restrict__ bq, const float* __restrict__ bk,
                const float* __restrict__ bv,
                u16* __restrict__ qb, u16* __restrict__ kb, u16* __restrict__ vtg,
                int M, int K, float scale_q)
{
    __shared__ __align__(16) u16 qsm[24576];  // 48KB: lA 3 bufs | lB 3 bufs
    u16* lA = qsm;            // bufs at 0, 4096, 8192
    u16* lB = qsm + 12288;    // bufs at 12288, 16384, 20480
    const int tid = threadIdx.x;
    const int w = tid >> 6, lane = tid & 63;
    const int quad = lane >> 4, l15 = lane & 15;
    const int m0 = blockIdx.x * 128, n0 = blockIdx.y * 128;
    const int wm = (w >> 1) * 64, wn = (w & 1) * 64;
    const int sw = (quad ^ ((l15 >> 1) & 3)) * 8;
    const int sel = blockIdx.y / 6;          // 0=q 1=k 2=v
    const int cl0 = n0 - sel * 768;
    const int dst = w * 512;

    const u16* pA[2]; const u16* pB[2];
    #pragma unroll
    for (int r = 0; r < 2; ++r) {
        int c = r * 256 + tid;
        int row = c >> 2, ch = (c & 3) ^ ((row >> 1) & 3);
        pA[r] = A + (size_t)(m0 + row) * K + ch * 8;
        pB[r] = Bt + (size_t)(n0 + row) * K + ch * 8;
    }

    const f32x4 fz = {0.f, 0.f, 0.f, 0.f};
    f32x4 acc[4][4];
    #pragma unroll
    for (int i = 0; i < 4; ++i)
        #pragma unroll
        for (int j = 0; j < 4; ++j) acc[i][j] = fz;

    #pragma unroll
    for (int p = 0; p < 2; ++p) {
        #pragma unroll
        for (int r = 0; r < 2; ++r) {
            async16(pA[r], lA + p * 4096 + r * 2048 + dst);
            async16(pB[r], lB + p * 4096 + r * 2048 + dst);
            pA[r] += 32; pB[r] += 32;
        }
    }

    const int nIt = K >> 5;
    int cur = 0;
    for (int it = 0; it < nIt; ++it) {
        if (it + 1 < nIt) asm volatile("s_waitcnt vmcnt(4)" ::: "memory");
        else              asm volatile("s_waitcnt vmcnt(0)" ::: "memory");
        __builtin_amdgcn_s_barrier();
        asm volatile("" ::: "memory");
        if (it + 2 < nIt) {
            int nb = cur + 2; if (nb >= 3) nb -= 3;
            #pragma unroll
            for (int r = 0; r < 2; ++r) {
                async16(pA[r], lA + nb * 4096 + r * 2048 + dst);
                async16(pB[r], lB + nb * 4096 + r * 2048 + dst);
                pA[r] += 32; pB[r] += 32;
            }
        }
        const u16* bA = lA + cur * 4096;
        const u16* bB = lB + cur * 4096;
        bf16x8 af[4], bfr[4];
        #pragma unroll
        for (int i = 0; i < 4; ++i)
            af[i] = *(const bf16x8*)&bA[(wm + i * 16 + l15) * 32 + sw];
        #pragma unroll
        for (int j = 0; j < 4; ++j)
            bfr[j] = *(const bf16x8*)&bB[(wn + j * 16 + l15) * 32 + sw];
        #pragma unroll
        for (int i = 0; i < 4; ++i)
            #pragma unroll
            for (int j = 0; j < 4; ++j)
                acc[i][j] = mfma16(af[i], bfr[j], acc[i][j]);
        asm volatile("" ::: "memory");
        cur = (cur + 1 == 3) ? 0 : cur + 1;
    }
    __syncthreads();  // full drain + barrier; safe to alias qsm below
    const float* bias = (sel == 0) ? bq : (sel == 1) ? bk : bv;
    if (sel < 2) {
        u16* out = (sel == 0) ? qb : kb;
        float sc = (sel == 0) ? scale_q : 1.f;
        #pragma unroll
        for (int j = 0; j < 4; ++j) {
            int cl = cl0 + wn + j * 16 + l15;
            float bvv = bias[cl];
            #pragma unroll
            for (int i = 0; i < 4; ++i) {
                int row = m0 + wm + i * 16 + quad * 4;
                #pragma unroll
                for (int r = 0; r < 4; ++r)
                    out[(size_t)(row + r) * 768 + cl] = f2bf((acc[i][j][r] + bvv) * sc);
            }
        }
    } else {
        // per-wave 64x64 transpose through LDS (stride 72, 16B-aligned rows)
        u16* lT = qsm + w * 4608;
        #pragma unroll
        for (int j = 0; j < 4; ++j) {
            float bvv = bias[cl0 + wn + j * 16 + l15];
            #pragma unroll
            for (int i = 0; i < 4; ++i)
                #pragma unroll
                for (int r = 0; r < 4; ++r)
                    lT[(j * 16 + l15) * 72 + i * 16 + quad * 4 + r]
                        = f2bf(acc[i][j][r] + bvv);
        }
        // wave-local DS ordering: reads below see the writes above
        int gcol = cl0 + wn + lane;
        u16* gdst = vtg + (size_t)gcol * M + m0 + wm;
        #pragma unroll
        for (int kk = 0; kk < 8; ++kk) {
            bf16x8 v = *(const bf16x8*)&lT[lane * 72 + kk * 8];
            *(bf16x8*)(gdst + kk * 8) = v;
        }
    }
}

// ------------------------------------------------------------- attention
// Fixed-max flash attention, S^T = K@Q^T trick. 4 waves = (wq: 2 q-halves)
// x (wk: 2 key-halves). KEY-PERMUTED K loading so QK^T output registers ARE
// the K=32 PV A-fragment (no P LDS bounce, no cross-lane ops).
// K LDS layout [kc][granule=quad][slot=swap23(row)] (conflict-free reads);
// l-sum via MFMA (pa x ones). XCD swizzle: K/V panels L2-resident
// (FETCH 108->22MB). Round-6 lesson: do NOT phase-pin this loop.
__global__ __launch_bounds__(256, 3)
void k_attention(const u16* __restrict__ Q, const u16* __restrict__ Kb,
                 const u16* __restrict__ Vt, u16* __restrict__ ctx,
                 int S, int D, int H, int M)
{
    __shared__ __align__(16) u16 sKV[16384];  // K0|K1|V0|V1, 4096 u16 each
    __shared__ float sL[2][64];
    const int o = xcd_swz(gridDim.x * gridDim.y);
    const int qt = o % gridDim.x, bh = o / gridDim.x;
    const int b = bh / H, h = bh % H;
    const int tid = threadIdx.x, w = tid >> 6, lane = tid & 63;
    const int wq = w & 1, wk = w >> 1;
    const int quad = lane >> 4, l15 = lane & 15;
    const int sw = (quad ^ ((l15 >> 1) & 3)) * 8;
    const size_t bS = (size_t)b * S;
    const int q0 = qt * 128 + wq * 64;

    // persistent Q B-frags: qrow = set*16+l15, dk = kc*32+quad*8
    bf16x8 qf[4][2];
    #pragma unroll
    for (int set = 0; set < 4; ++set)
        #pragma unroll
        for (int kc = 0; kc < 2; ++kc)
            qf[set][kc] = *(const bf16x8*)(Q + (bS + q0 + set * 16 + l15) * D
                                           + (size_t)h * 64 + kc * 32 + quad * 8);

    const f32x4 fz = {0.f, 0.f, 0.f, 0.f};
    f32x4 O[4][4], Ol[4];
    #pragma unroll
    for (int s = 0; s < 4; ++s) {
        Ol[s] = fz;
        #pragma unroll
        for (int j = 0; j < 4; ++j) O[s][j] = fz;
    }
    union { u16 s[8]; bf16x8 v; } one8;
    #pragma unroll
    for (int i = 0; i < 8; ++i) one8.s[i] = 0x3F80;  // bf16 1.0

    const u16* kbase = Kb + bS * D + (size_t)h * 64;
    const u16* vbase = Vt + (size_t)h * 64 * M + bS;

    // staging sources. K: wave w stages dk-granule w; lane ell fetches row
    // swap23(ell) so LDS slot s holds row swap23(s). V: unchanged.
    const int rsw = (lane & ~12) | ((lane & 4) << 1) | ((lane & 8) >> 1);
    const u16* gk[2]; const u16* gv[2];
    #pragma unroll
    for (int i = 0; i < 2; ++i) {
        gk[i] = kbase + (size_t)rsw * D + i * 32 + w * 8;
        int c = i * 256 + tid;
        int dk = (c >> 2) & 63, vch = (c & 3) ^ ((dk >> 1) & 3);
        gv[i] = vbase + (size_t)dk * M + i * 32 + vch * 8;
    }
    const int dslot = w * 512;  // wave-uniform LDS chunk base (u16)

    // prologue: stage tile 0 into buffer 0
    #pragma unroll
    for (int i = 0; i < 2; ++i) {
        async16(gk[i], sKV + i * 2048 + dslot);
        async16(gv[i], sKV + 8192 + i * 2048 + dslot);
        gk[i] += (size_t)64 * D;
        gv[i] += 64;
    }

    // key-permuted K A-frag LDS offsets (granule = quad, slot = swap23(row))
    int ksl[2];
    #pragma unroll
    for (int ks = 0; ks < 2; ++ks) {
        int row64 = wk * 32 + ((l15 >> 2) << 3) + ks * 4 + (l15 & 3);
        int s = (row64 & ~12) | ((row64 & 4) << 1) | ((row64 & 8) >> 1);
        ksl[ks] = quad * 512 + s * 8;
    }

    const int T = S >> 6;
    for (int t = 0; t < T; ++t) {
        __syncthreads();  // buf[t&1] staged; all prior LDS reads drained
        if (t + 1 < T) {
            int nb = (t + 1) & 1;
            #pragma unroll
            for (int i = 0; i < 2; ++i) {
                async16(gk[i], sKV + nb * 4096 + i * 2048 + dslot);
                async16(gv[i], sKV + 8192 + nb * 4096 + i * 2048 + dslot);
                gk[i] += (size_t)64 * D;
                gv[i] += 64;
            }
        }
        const u16* lKb = sKV + (t & 1) * 4096;
        const u16* lVb = sKV + 8192 + (t & 1) * 4096;

        // wave's 32 keys (permuted rows): A-row l15 of ka[ks] = key row64(ks)
        bf16x8 ka[2][2], vf[4];
        #pragma unroll
        for (int ks = 0; ks < 2; ++ks)
            #pragma unroll
            for (int kc = 0; kc < 2; ++kc)
                ka[ks][kc] = *(const bf16x8*)&lKb[kc * 2048 + ksl[ks]];
        #pragma unroll
        for (int dj = 0; dj < 4; ++dj)
            vf[dj] = *(const bf16x8*)
                &lVb[wk * 2048 + (dj * 16 + l15) * 32 + sw];

        #pragma unroll
        for (int set = 0; set < 4; ++set) {
            f32x4 sc0 = fz, sc1 = fz;
            __builtin_amdgcn_s_setprio(1);
            sc0 = mfma16(ka[0][0], qf[set][0], sc0);
            sc0 = mfma16(ka[0][1], qf[set][1], sc0);
            sc1 = mfma16(ka[1][0], qf[set][0], sc1);
            sc1 = mfma16(ka[1][1], qf[set][1], sc1);
            __builtin_amdgcn_s_setprio(0);
            // lane now holds keys quad*8..+3 (sc0) and quad*8+4..+7 (sc1)
            float p0[4], p1[4];
            #pragma unroll
            for (int r = 0; r < 4; ++r) {
                p0[r] = __builtin_amdgcn_exp2f(sc0[r]);
                p1[r] = __builtin_amdgcn_exp2f(sc1[r]);
            }
            union { uint32_t u[4]; bf16x8 v; } pa;
            pa.u[0] = pack_bf2(p0[0], p0[1]); pa.u[1] = pack_bf2(p0[2], p0[3]);
            pa.u[2] = pack_bf2(p1[0], p1[1]); pa.u[3] = pack_bf2(p1[2], p1[3]);
            __builtin_amdgcn_s_setprio(1);
            #pragma unroll
            for (int dj = 0; dj < 4; ++dj)
                O[set][dj] = mfma16(pa.v, vf[dj], O[set][dj]);
            Ol[set] = mfma16(pa.v, one8.v, Ol[set]);
            __builtin_amdgcn_s_setprio(0);
        }
    }

    // Ol[set][r] = sum over this wave's 32 keys for qrow set*16+quad*4+r
    // (replicated across l15). Cross-wk combine via sL; no shuffles needed.
    __syncthreads();  // all compute reads drained; safe to alias staging LDS
    u16* lO = sKV;    // [qrow128][dk64+2pad] bf16 = 8448 u16
    if (wk == 1) {
        #pragma unroll
        for (int set = 0; set < 4; ++set) {
            #pragma unroll
            for (int dj = 0; dj < 4; ++dj)
                #pragma unroll
                for (int r = 0; r < 4; ++r)
                    lO[(wq * 64 + set * 16 + quad * 4 + r) * 66 + dj * 16 + l15]
                        = f2bf(O[set][dj][r]);
            if (l15 == 0) {
                #pragma unroll
                for (int r = 0; r < 4; ++r)
                    sL[wq][set * 16 + quad * 4 + r] = Ol[set][r];
            }
        }
    }
    __syncthreads();
    if (wk == 0) {
        #pragma unroll
        for (int set = 0; set < 4; ++set) {
            float rl[4];
            #pragma unroll
            for (int r = 0; r < 4; ++r)
                rl[r] = 1.f / (Ol[set][r] + sL[wq][set * 16 + quad * 4 + r]);
            #pragma unroll
            for (int dj = 0; dj < 4; ++dj)
                #pragma unroll
                for (int r = 0; r < 4; ++r) {
                    float o = O[set][dj][r]
                        + bf2f(lO[(wq * 64 + set * 16 + quad * 4 + r) * 66 + dj * 16 + l15]);
                    ctx[(bS + q0 + set * 16 + quad * 4 + r) * D
                        + (size_t)h * 64 + dj * 16 + l15] = f2bf(o * rl[r]);
                }
        }
    }
}

// -------------------------------------------- layernorm over sum of parts
__global__ __launch_bounds__(256)
void k_layernorm2(const float* __restrict__ p0, const float* __restrict__ p1,
                  const float* __restrict__ resid, const float* __restrict__ bias,
                  const float* __restrict__ a, const float* __restrict__ g,
                  float* __restrict__ outf, u16* __restrict__ outb, int D)
{
    const int row = blockIdx.x, tid = threadIdx.x;
    const size_t base = (size_t)row * D;
    float v[3];
    float s = 0.f, sq = 0.f;
    #pragma unroll
    for (int i = 0; i < 3; ++i) {
        int c = tid + i * 256;
        float x = p0[base + c] + p1[base + c] + resid[base + c] + bias[c];
        v[i] = x; s += x; sq += x * x;
    }
    #pragma unroll
    for (int off = 32; off >= 1; off >>= 1) {
        s += __shfl_xor(s, off, 64);
        sq += __shfl_xor(sq, off, 64);
    }
    __shared__ float red[8];
    const int w = tid >> 6;
    if ((tid & 63) == 0) { red[w] = s; red[4 + w] = sq; }
    __syncthreads();
    s = red[0] + red[1] + red[2] + red[3];
    sq = red[4] + red[5] + red[6] + red[7];
    float mean = s / D;
    float var = fmaxf((sq - s * mean) / (D - 1), 0.f);
    float denom = sqrtf(var) + 1e-5f;
    float av = a[0], gv = g[0];
    #pragma unroll
    for (int i = 0; i < 3; ++i) {
        float y = av * ((v[i] - mean) / denom) + gv;
        if (outf) outf[base + tid + i * 256] = y;
        if (outb) outb[base + tid + i * 256] = f2bf(y);
    }
}

// ---------------------------------------------------------------- launch
extern "C" void kernel_launch(void* const* d_in, const int* in_sizes, int n_in,
                              void* d_out, int out_size, void* d_ws, size_t ws_size,
                              hipStream_t stream)
{
    constexpr int B = 2, S = 4096, D = 768, H = 12, F = 3072;
    constexpr int M = B * S;
    const float SCALE_Q = 1.4426950408889634f / 8.0f;  // log2(e)/sqrt(dk)
    const float* x  = (const float*)d_in[0];
    const float* wq = (const float*)d_in[1];
    const float* bq = (const float*)d_in[2];
    const float* wk = (const float*)d_in[3];
    const float* bk = (const float*)d_in[4];
    const float* wv = (const float*)d_in[5];
    const float* bv = (const float*)d_in[6];
    const float* wo = (const float*)d_in[7];
    const float* bo = (const float*)d_in[8];
    const float* w1 = (const float*)d_in[9];
    const float* b1 = (const float*)d_in[10];
    const float* w2 = (const float*)d_in[11];
    const float* b2 = (const float*)d_in[12];
    const float* a1 = (const float*)d_in[13];
    const float* g1 = (const float*)d_in[14];
    const float* a2 = (const float*)d_in[15];
    const float* g2 = (const float*)d_in[16];

    char* ws = (char*)d_ws;
    size_t off = 0;
    auto alloc = [&](size_t bytes) {
        void* p = ws + off;
        off = (off + bytes + 255) & ~(size_t)255;
        return p;
    };
    u16*   xb    = (u16*)alloc((size_t)M * D * 2);
    u16*   wqkvt = (u16*)alloc((size_t)3 * D * D * 2);
    u16*   wot   = (u16*)alloc((size_t)D * D * 2);
    u16*   w1t   = (u16*)alloc((size_t)D * F * 2);
    u16*   w2t   = (u16*)alloc((size_t)D * F * 2);
    u16*   qb    = (u16*)alloc((size_t)M * D * 2);
    u16*   kb    = (u16*)alloc((size_t)M * D * 2);
    u16*   vtg   = (u16*)alloc((size_t)M * D * 2);  // V transposed: [D][M]
    u16*   ctxb  = (u16*)alloc((size_t)M * D * 2);
    float* x1f   = (float*)alloc((size_t)M * D * 4);
    u16*   x1b   = (u16*)alloc((size_t)M * D * 2);
    u16*   ff1b  = (u16*)alloc((size_t)M * F * 2);

    float* p0a = (float*)qb;     // WO partial 0 over qb+kb   (dead after attn)
    float* p1a = (float*)ff1b;   // WO partial 1 over ff1b    (not yet live)
    float* p0b = (float*)qb;     // FF2 partial 0 over qb+kb
    float* p1b = (float*)vtg;    // FF2 partial 1 over vtg+ctxb (dead after WO)

    k_prep<<<6144 + 6912, 256, 0, stream>>>(x, xb, wq, wk, wv, wo, w1, w2,
                                            wqkvt, wot, w1t, w2t);

    k_gemm_qkv<<<dim3(M / 128, 3 * D / 128), 256, 0, stream>>>(
        xb, wqkvt, bq, bk, bv, qb, kb, vtg, M, D, SCALE_Q);

    k_attention<<<dim3(S / 128, B * H), 256, 0, stream>>>(qb, kb, vtg, ctxb, S, D, H, M);

    k_gemm_part256<<<dim3(M / 256, D / 256, 2), 512, 0, stream>>>(
        ctxb, wot, p0a, p1a, M, D, D, D / 2);
    k_layernorm2<<<M, 256, 0, stream>>>(p0a, p1a, x, bo, a1, g1, x1f, x1b, D);

    k_gemm256<true><<<dim3(M / 256, F / 256), 512, 0, stream>>>(
        x1b, w1t, b1, ff1b, M, F, D);
    k_gemm_part256<<<dim3(M / 256, D / 256, 2), 512, 0, stream>>>(
        ff1b, w2t, p0b, p1b, M, D, F, F / 2);
    k_layernorm2<<<M, 256, 0, stream>>>(p0b, p1b, x1f, b2, a2, g2, (float*)d_out, nullptr, D);

    (void)in_sizes; (void)n_in; (void)out_size; (void)ws_size;
}

// Round 11
// 418.751 us; speedup vs baseline: 1.1574x; 1.1574x over previous
//
#include <hip/hip_runtime.h>
#include <hip/hip_bf16.h>
#include <cstdint>
#include <cstddef>

typedef unsigned short u16;
typedef __attribute__((ext_vector_type(8))) __bf16 bf16x8;
typedef __attribute__((ext_vector_type(4))) float f32x4;

#define AS1 __attribute__((address_space(1)))
#define AS3 __attribute__((address_space(3)))

__device__ __forceinline__ u16 f2bf(float f) {
    union { float f; uint32_t u; } v; v.f = f;
    uint32_t r = (v.u + 0x7FFFu + ((v.u >> 16) & 1u)) >> 16;
    return (u16)r;
}

__device__ __forceinline__ float bf2f(u16 b) {
    union { uint32_t u; float f; } v; v.u = ((uint32_t)b) << 16;
    return v.f;
}

// single-instruction RNE pack of two f32 -> packed bf16x2 (no builtin on
// gfx950; __float22bfloat162_rn lowers to a ~6-instr software sequence).
__device__ __forceinline__ uint32_t cvtpk_bf2(float lo, float hi) {
    uint32_t r;
    asm("v_cvt_pk_bf16_f32 %0, %1, %2" : "=v"(r) : "v"(lo), "v"(hi));
    return r;
}

__device__ __forceinline__ f32x4 mfma16(bf16x8 a, bf16x8 b, f32x4 c) {
    return __builtin_amdgcn_mfma_f32_16x16x32_bf16(a, b, c, 0, 0, 0);
}

// async global->LDS, 16B per lane; lane i lands at base + i*16.
__device__ __forceinline__ void async16(const u16* g, u16* lds_uniform_base) {
    __builtin_amdgcn_global_load_lds((const AS1 void*)g, (AS3 void*)lds_uniform_base, 16, 0, 0);
}

// XCD-aware block remap for ATTENTION ONLY (requires nwg % 8 == 0).
// Round-7 measurement: natural round-robin already partitions GEMM bx per
// XCD; chunked remap there cost ~30us. Attention's shared K/V is indexed by
// the SLOW coord -> chunked remap wins (FETCH 108->22MB).
// Round-10 lesson: 256^2 GEMM tiles under-subscribe the grid (192 blocks on
// 256 CUs) -> keep 128^2 tiles; GEMM family is MFMA-structure-bound, not
// BW-bound (L3 caches the operand panels).
__device__ __forceinline__ int xcd_swz(int nwg) {
    int b = blockIdx.x + gridDim.x * (blockIdx.y + gridDim.y * blockIdx.z);
    return (b & 7) * (nwg >> 3) + (b >> 3);
}

// ------------------------------------------------------------ fused prep
__global__ __launch_bounds__(256)
void k_prep(const float* __restrict__ x, u16* __restrict__ xb,
            const float* __restrict__ wq, const float* __restrict__ wk,
            const float* __restrict__ wv, const float* __restrict__ wo,
            const float* __restrict__ w1, const float* __restrict__ w2,
            u16* __restrict__ wqkvt, u16* __restrict__ wot,
            u16* __restrict__ w1t, u16* __restrict__ w2t)
{
    int bx = blockIdx.x;
    if (bx < 6144) {
        int i = (bx * 256 + threadIdx.x) * 4;
        float4 f = *(const float4*)(x + i);
        xb[i + 0] = f2bf(f.x); xb[i + 1] = f2bf(f.y);
        xb[i + 2] = f2bf(f.z); xb[i + 3] = f2bf(f.w);
        return;
    }
    int t = bx - 6144;
    const float* in; u16* out; int R, C;
    if (t < 2304) {
        int m = t / 576; t -= m * 576;
        R = 768; C = 768;
        in = (m == 0) ? wq : (m == 1) ? wk : (m == 2) ? wv : wo;
        out = (m < 3) ? wqkvt + (size_t)m * 768 * 768 : wot;
    } else if (t < 4608) {
        t -= 2304; in = w1; out = w1t; R = 768; C = 3072;
    } else {
        t -= 4608; in = w2; out = w2t; R = 3072; C = 768;
    }
    int tilesX = C >> 5;
    int c0 = (t % tilesX) * 32, r0 = (t / tilesX) * 32;
    __shared__ float tile[32][33];
    int tx = threadIdx.x & 31, ty = threadIdx.x >> 5;
    #pragma unroll
    for (int i = ty; i < 32; i += 8)
        tile[i][tx] = in[(size_t)(r0 + i) * C + c0 + tx];
    __syncthreads();
    #pragma unroll
    for (int i = ty; i < 32; i += 8)
        out[(size_t)(c0 + i) * R + r0 + tx] = f2bf(tile[tx][i]);
}

// ---------------------------------------------------------------- GEMM
// Triple-buffered, depth-2 prefetch, COUNTED vmcnt + raw s_barrier (round-9
// best). Tile it+2 issued at iter it (2 iters of flight); each wave waits
// only its OWN 4 oldest loads (vmcnt(4)); raw barrier does not drain.
template <bool RELU>
__global__ __launch_bounds__(256)
void k_gemm(const u16* __restrict__ A, const u16* __restrict__ Bt,
            const float* __restrict__ bias, u16* __restrict__ Cb,
            int M, int N, int K)
{
    __shared__ __align__(16) u16 lA[3 * 4096];
    __shared__ __align__(16) u16 lB[3 * 4096];
    const int tid = threadIdx.x;
    const int w = tid >> 6, lane = tid & 63;
    const int quad = lane >> 4, l15 = lane & 15;
    const int m0 = blockIdx.x * 128, n0 = blockIdx.y * 128;
    const int wm = (w >> 1) * 64, wn = (w & 1) * 64;
    const int sw = (quad ^ ((l15 >> 1) & 3)) * 8;
    const int dst = w * 512;   // wave-uniform LDS chunk base (u16)

    const u16* pA[2]; const u16* pB[2];
    #pragma unroll
    for (int r = 0; r < 2; ++r) {
        int c = r * 256 + tid;
        int row = c >> 2, ch = (c & 3) ^ ((row >> 1) & 3);
        pA[r] = A + (size_t)(m0 + row) * K + ch * 8;
        pB[r] = Bt + (size_t)(n0 + row) * K + ch * 8;
    }

    const f32x4 fz = {0.f, 0.f, 0.f, 0.f};
    f32x4 acc[4][4];
    #pragma unroll
    for (int i = 0; i < 4; ++i)
        #pragma unroll
        for (int j = 0; j < 4; ++j) acc[i][j] = fz;

    // prologue: issue tiles 0 and 1
    #pragma unroll
    for (int p = 0; p < 2; ++p) {
        #pragma unroll
        for (int r = 0; r < 2; ++r) {
            async16(pA[r], lA + p * 4096 + r * 2048 + dst);
            async16(pB[r], lB + p * 4096 + r * 2048 + dst);
            pA[r] += 32; pB[r] += 32;
        }
    }

    const int nIt = K >> 5;
    int cur = 0;
    for (int it = 0; it < nIt; ++it) {
        if (it + 1 < nIt) asm volatile("s_waitcnt vmcnt(4)" ::: "memory");
        else              asm volatile("s_waitcnt vmcnt(0)" ::: "memory");
        __builtin_amdgcn_s_barrier();
        asm volatile("" ::: "memory");
        if (it + 2 < nIt) {
            int nb = cur + 2; if (nb >= 3) nb -= 3;
            #pragma unroll
            for (int r = 0; r < 2; ++r) {
                async16(pA[r], lA + nb * 4096 + r * 2048 + dst);
                async16(pB[r], lB + nb * 4096 + r * 2048 + dst);
                pA[r] += 32; pB[r] += 32;
            }
        }
        const u16* bA = lA + cur * 4096;
        const u16* bB = lB + cur * 4096;
        bf16x8 af[4], bfr[4];
        #pragma unroll
        for (int i = 0; i < 4; ++i)
            af[i] = *(const bf16x8*)&bA[(wm + i * 16 + l15) * 32 + sw];
        #pragma unroll
        for (int j = 0; j < 4; ++j)
            bfr[j] = *(const bf16x8*)&bB[(wn + j * 16 + l15) * 32 + sw];
        #pragma unroll
        for (int i = 0; i < 4; ++i)
            #pragma unroll
            for (int j = 0; j < 4; ++j)
                acc[i][j] = mfma16(af[i], bfr[j], acc[i][j]);
        asm volatile("" ::: "memory");
        cur = (cur + 1 == 3) ? 0 : cur + 1;
    }
    #pragma unroll
    for (int j = 0; j < 4; ++j) {
        int col = n0 + wn + j * 16 + l15;
        float bv = bias[col];
        #pragma unroll
        for (int i = 0; i < 4; ++i) {
            int row = m0 + wm + i * 16 + quad * 4;
            #pragma unroll
            for (int r = 0; r < 4; ++r) {
                float t = acc[i][j][r] + bv;
                if (RELU) t = fmaxf(t, 0.f);
                Cb[(size_t)(row + r) * N + col] = f2bf(t);
            }
        }
    }
}

// ------------------------------------------------- split-K partial GEMM
__global__ __launch_bounds__(256)
void k_gemm_part(const u16* __restrict__ A, const u16* __restrict__ Bt,
                 float* __restrict__ C0, float* __restrict__ C1,
                 int M, int N, int K, int Kh)
{
    __shared__ __align__(16) u16 lA[3 * 4096];
    __shared__ __align__(16) u16 lB[3 * 4096];
    const int tid = threadIdx.x;
    const int w = tid >> 6, lane = tid & 63;
    const int quad = lane >> 4, l15 = lane & 15;
    const int m0 = blockIdx.x * 128, n0 = blockIdx.y * 128;
    const int wm = (w >> 1) * 64, wn = (w & 1) * 64;
    const int sw = (quad ^ ((l15 >> 1) & 3)) * 8;
    const int kbeg = blockIdx.z * Kh;
    float* __restrict__ C = blockIdx.z ? C1 : C0;
    const int dst = w * 512;

    const u16* pA[2]; const u16* pB[2];
    #pragma unroll
    for (int r = 0; r < 2; ++r) {
        int c = r * 256 + tid;
        int row = c >> 2, ch = (c & 3) ^ ((row >> 1) & 3);
        pA[r] = A + (size_t)(m0 + row) * K + kbeg + ch * 8;
        pB[r] = Bt + (size_t)(n0 + row) * K + kbeg + ch * 8;
    }

    const f32x4 fz = {0.f, 0.f, 0.f, 0.f};
    f32x4 acc[4][4];
    #pragma unroll
    for (int i = 0; i < 4; ++i)
        #pragma unroll
        for (int j = 0; j < 4; ++j) acc[i][j] = fz;

    #pragma unroll
    for (int p = 0; p < 2; ++p) {
        #pragma unroll
        for (int r = 0; r < 2; ++r) {
            async16(pA[r], lA + p * 4096 + r * 2048 + dst);
            async16(pB[r], lB + p * 4096 + r * 2048 + dst);
            pA[r] += 32; pB[r] += 32;
        }
    }

    const int nIt = Kh >> 5;
    int cur = 0;
    for (int it = 0; it < nIt; ++it) {
        if (it + 1 < nIt) asm volatile("s_waitcnt vmcnt(4)" ::: "memory");
        else              asm volatile("s_waitcnt vmcnt(0)" ::: "memory");
        __builtin_amdgcn_s_barrier();
        asm volatile("" ::: "memory");
        if (it + 2 < nIt) {
            int nb = cur + 2; if (nb >= 3) nb -= 3;
            #pragma unroll
            for (int r = 0; r < 2; ++r) {
                async16(pA[r], lA + nb * 4096 + r * 2048 + dst);
                async16(pB[r], lB + nb * 4096 + r * 2048 + dst);
                pA[r] += 32; pB[r] += 32;
            }
        }
        const u16* bA = lA + cur * 4096;
        const u16* bB = lB + cur * 4096;
        bf16x8 af[4], bfr[4];
        #pragma unroll
        for (int i = 0; i < 4; ++i)
            af[i] = *(const bf16x8*)&bA[(wm + i * 16 + l15) * 32 + sw];
        #pragma unroll
        for (int j = 0; j < 4; ++j)
            bfr[j] = *(const bf16x8*)&bB[(wn + j * 16 + l15) * 32 + sw];
        #pragma unroll
        for (int i = 0; i < 4; ++i)
            #pragma unroll
            for (int j = 0; j < 4; ++j)
                acc[i][j] = mfma16(af[i], bfr[j], acc[i][j]);
        asm volatile("" ::: "memory");
        cur = (cur + 1 == 3) ? 0 : cur + 1;
    }
    #pragma unroll
    for (int j = 0; j < 4; ++j) {
        int col = n0 + wn + j * 16 + l15;
        #pragma unroll
        for (int i = 0; i < 4; ++i) {
            int row = m0 + wm + i * 16 + quad * 4;
            #pragma unroll
            for (int r = 0; r < 4; ++r)
                C[(size_t)(row + r) * N + col] = acc[i][j][r];
        }
    }
}

// ------------------------------------------------------ fused QKV GEMM
// sel==2 (V): output written TRANSPOSED to vtg[D][M] via per-wave LDS
// transpose -> 16B contiguous global stores. Triple-buffered staging in
// qsm[0..24576); V-transpose (after trailing full __syncthreads) aliases
// the staging area.
__global__ __launch_bounds__(256)
void k_gemm_qkv(const u16* __restrict__ A, const u16* __restrict__ Bt,
                const float* __restrict__ bq, const float* __restrict__ bk,
                const float* __restrict__ bv,
                u16* __restrict__ qb, u16* __restrict__ kb, u16* __restrict__ vtg,
                int M, int K, float scale_q)
{
    __shared__ __align__(16) u16 qsm[24576];  // 48KB: lA 3 bufs | lB 3 bufs
    u16* lA = qsm;            // bufs at 0, 4096, 8192
    u16* lB = qsm + 12288;    // bufs at 12288, 16384, 20480
    const int tid = threadIdx.x;
    const int w = tid >> 6, lane = tid & 63;
    const int quad = lane >> 4, l15 = lane & 15;
    const int m0 = blockIdx.x * 128, n0 = blockIdx.y * 128;
    const int wm = (w >> 1) * 64, wn = (w & 1) * 64;
    const int sw = (quad ^ ((l15 >> 1) & 3)) * 8;
    const int sel = blockIdx.y / 6;          // 0=q 1=k 2=v
    const int cl0 = n0 - sel * 768;
    const int dst = w * 512;

    const u16* pA[2]; const u16* pB[2];
    #pragma unroll
    for (int r = 0; r < 2; ++r) {
        int c = r * 256 + tid;
        int row = c >> 2, ch = (c & 3) ^ ((row >> 1) & 3);
        pA[r] = A + (size_t)(m0 + row) * K + ch * 8;
        pB[r] = Bt + (size_t)(n0 + row) * K + ch * 8;
    }

    const f32x4 fz = {0.f, 0.f, 0.f, 0.f};
    f32x4 acc[4][4];
    #pragma unroll
    for (int i = 0; i < 4; ++i)
        #pragma unroll
        for (int j = 0; j < 4; ++j) acc[i][j] = fz;

    #pragma unroll
    for (int p = 0; p < 2; ++p) {
        #pragma unroll
        for (int r = 0; r < 2; ++r) {
            async16(pA[r], lA + p * 4096 + r * 2048 + dst);
            async16(pB[r], lB + p * 4096 + r * 2048 + dst);
            pA[r] += 32; pB[r] += 32;
        }
    }

    const int nIt = K >> 5;
    int cur = 0;
    for (int it = 0; it < nIt; ++it) {
        if (it + 1 < nIt) asm volatile("s_waitcnt vmcnt(4)" ::: "memory");
        else              asm volatile("s_waitcnt vmcnt(0)" ::: "memory");
        __builtin_amdgcn_s_barrier();
        asm volatile("" ::: "memory");
        if (it + 2 < nIt) {
            int nb = cur + 2; if (nb >= 3) nb -= 3;
            #pragma unroll
            for (int r = 0; r < 2; ++r) {
                async16(pA[r], lA + nb * 4096 + r * 2048 + dst);
                async16(pB[r], lB + nb * 4096 + r * 2048 + dst);
                pA[r] += 32; pB[r] += 32;
            }
        }
        const u16* bA = lA + cur * 4096;
        const u16* bB = lB + cur * 4096;
        bf16x8 af[4], bfr[4];
        #pragma unroll
        for (int i = 0; i < 4; ++i)
            af[i] = *(const bf16x8*)&bA[(wm + i * 16 + l15) * 32 + sw];
        #pragma unroll
        for (int j = 0; j < 4; ++j)
            bfr[j] = *(const bf16x8*)&bB[(wn + j * 16 + l15) * 32 + sw];
        #pragma unroll
        for (int i = 0; i < 4; ++i)
            #pragma unroll
            for (int j = 0; j < 4; ++j)
                acc[i][j] = mfma16(af[i], bfr[j], acc[i][j]);
        asm volatile("" ::: "memory");
        cur = (cur + 1 == 3) ? 0 : cur + 1;
    }
    __syncthreads();  // full drain + barrier; safe to alias qsm below
    const float* bias = (sel == 0) ? bq : (sel == 1) ? bk : bv;
    if (sel < 2) {
        u16* out = (sel == 0) ? qb : kb;
        float sc = (sel == 0) ? scale_q : 1.f;
        #pragma unroll
        for (int j = 0; j < 4; ++j) {
            int cl = cl0 + wn + j * 16 + l15;
            float bvv = bias[cl];
            #pragma unroll
            for (int i = 0; i < 4; ++i) {
                int row = m0 + wm + i * 16 + quad * 4;
                #pragma unroll
                for (int r = 0; r < 4; ++r)
                    out[(size_t)(row + r) * 768 + cl] = f2bf((acc[i][j][r] + bvv) * sc);
            }
        }
    } else {
        // per-wave 64x64 transpose through LDS (stride 72, 16B-aligned rows)
        u16* lT = qsm + w * 4608;
        #pragma unroll
        for (int j = 0; j < 4; ++j) {
            float bvv = bias[cl0 + wn + j * 16 + l15];
            #pragma unroll
            for (int i = 0; i < 4; ++i)
                #pragma unroll
                for (int r = 0; r < 4; ++r)
                    lT[(j * 16 + l15) * 72 + i * 16 + quad * 4 + r]
                        = f2bf(acc[i][j][r] + bvv);
        }
        // wave-local DS ordering: reads below see the writes above
        int gcol = cl0 + wn + lane;
        u16* gdst = vtg + (size_t)gcol * M + m0 + wm;
        #pragma unroll
        for (int kk = 0; kk < 8; ++kk) {
            bf16x8 v = *(const bf16x8*)&lT[lane * 72 + kk * 8];
            *(bf16x8*)(gdst + kk * 8) = v;
        }
    }
}

// ------------------------------------------------------------- attention
// Fixed-max flash attention, S^T = K@Q^T trick. 4 waves = (wq: 2 q-halves)
// x (wk: 2 key-halves). KEY-PERMUTED K loading so QK^T output registers ARE
// the K=32 PV A-fragment (no P LDS bounce, no cross-lane ops).
// K LDS layout [kc][granule=quad][slot=swap23(row)] (conflict-free reads);
// l-sum via MFMA (pa x ones). XCD swizzle: K/V panels L2-resident
// (FETCH 108->22MB). Round-6 lesson: do NOT phase-pin this loop.
// P pack via single-instruction v_cvt_pk_bf16_f32 (RNE, bit-identical to
// __float22bfloat162_rn on finite values) -- removes ~80 VALU/tile/wave of
// software-RNE sequence (VALUBusy was 45% with ~2x unexplained VALU).
__global__ __launch_bounds__(256, 3)
void k_attention(const u16* __restrict__ Q, const u16* __restrict__ Kb,
                 const u16* __restrict__ Vt, u16* __restrict__ ctx,
                 int S, int D, int H, int M)
{
    __shared__ __align__(16) u16 sKV[16384];  // K0|K1|V0|V1, 4096 u16 each
    __shared__ float sL[2][64];
    const int o = xcd_swz(gridDim.x * gridDim.y);
    const int qt = o % gridDim.x, bh = o / gridDim.x;
    const int b = bh / H, h = bh % H;
    const int tid = threadIdx.x, w = tid >> 6, lane = tid & 63;
    const int wq = w & 1, wk = w >> 1;
    const int quad = lane >> 4, l15 = lane & 15;
    const int sw = (quad ^ ((l15 >> 1) & 3)) * 8;
    const size_t bS = (size_t)b * S;
    const int q0 = qt * 128 + wq * 64;

    // persistent Q B-frags: qrow = set*16+l15, dk = kc*32+quad*8
    bf16x8 qf[4][2];
    #pragma unroll
    for (int set = 0; set < 4; ++set)
        #pragma unroll
        for (int kc = 0; kc < 2; ++kc)
            qf[set][kc] = *(const bf16x8*)(Q + (bS + q0 + set * 16 + l15) * D
                                           + (size_t)h * 64 + kc * 32 + quad * 8);

    const f32x4 fz = {0.f, 0.f, 0.f, 0.f};
    f32x4 O[4][4], Ol[4];
    #pragma unroll
    for (int s = 0; s < 4; ++s) {
        Ol[s] = fz;
        #pragma unroll
        for (int j = 0; j < 4; ++j) O[s][j] = fz;
    }
    union { u16 s[8]; bf16x8 v; } one8;
    #pragma unroll
    for (int i = 0; i < 8; ++i) one8.s[i] = 0x3F80;  // bf16 1.0

    const u16* kbase = Kb + bS * D + (size_t)h * 64;
    const u16* vbase = Vt + (size_t)h * 64 * M + bS;

    // staging sources. K: wave w stages dk-granule w; lane ell fetches row
    // swap23(ell) so LDS slot s holds row swap23(s). V: unchanged.
    const int rsw = (lane & ~12) | ((lane & 4) << 1) | ((lane & 8) >> 1);
    const u16* gk[2]; const u16* gv[2];
    #pragma unroll
    for (int i = 0; i < 2; ++i) {
        gk[i] = kbase + (size_t)rsw * D + i * 32 + w * 8;
        int c = i * 256 + tid;
        int dk = (c >> 2) & 63, vch = (c & 3) ^ ((dk >> 1) & 3);
        gv[i] = vbase + (size_t)dk * M + i * 32 + vch * 8;
    }
    const int dslot = w * 512;  // wave-uniform LDS chunk base (u16)

    // prologue: stage tile 0 into buffer 0
    #pragma unroll
    for (int i = 0; i < 2; ++i) {
        async16(gk[i], sKV + i * 2048 + dslot);
        async16(gv[i], sKV + 8192 + i * 2048 + dslot);
        gk[i] += (size_t)64 * D;
        gv[i] += 64;
    }

    // key-permuted K A-frag LDS offsets (granule = quad, slot = swap23(row))
    int ksl[2];
    #pragma unroll
    for (int ks = 0; ks < 2; ++ks) {
        int row64 = wk * 32 + ((l15 >> 2) << 3) + ks * 4 + (l15 & 3);
        int s = (row64 & ~12) | ((row64 & 4) << 1) | ((row64 & 8) >> 1);
        ksl[ks] = quad * 512 + s * 8;
    }

    const int T = S >> 6;
    for (int t = 0; t < T; ++t) {
        __syncthreads();  // buf[t&1] staged; all prior LDS reads drained
        if (t + 1 < T) {
            int nb = (t + 1) & 1;
            #pragma unroll
            for (int i = 0; i < 2; ++i) {
                async16(gk[i], sKV + nb * 4096 + i * 2048 + dslot);
                async16(gv[i], sKV + 8192 + nb * 4096 + i * 2048 + dslot);
                gk[i] += (size_t)64 * D;
                gv[i] += 64;
            }
        }
        const u16* lKb = sKV + (t & 1) * 4096;
        const u16* lVb = sKV + 8192 + (t & 1) * 4096;

        // wave's 32 keys (permuted rows): A-row l15 of ka[ks] = key row64(ks)
        bf16x8 ka[2][2], vf[4];
        #pragma unroll
        for (int ks = 0; ks < 2; ++ks)
            #pragma unroll
            for (int kc = 0; kc < 2; ++kc)
                ka[ks][kc] = *(const bf16x8*)&lKb[kc * 2048 + ksl[ks]];
        #pragma unroll
        for (int dj = 0; dj < 4; ++dj)
            vf[dj] = *(const bf16x8*)
                &lVb[wk * 2048 + (dj * 16 + l15) * 32 + sw];

        #pragma unroll
        for (int set = 0; set < 4; ++set) {
            f32x4 sc0 = fz, sc1 = fz;
            __builtin_amdgcn_s_setprio(1);
            sc0 = mfma16(ka[0][0], qf[set][0], sc0);
            sc0 = mfma16(ka[0][1], qf[set][1], sc0);
            sc1 = mfma16(ka[1][0], qf[set][0], sc1);
            sc1 = mfma16(ka[1][1], qf[set][1], sc1);
            __builtin_amdgcn_s_setprio(0);
            // lane now holds keys quad*8..+3 (sc0) and quad*8+4..+7 (sc1)
            float p0[4], p1[4];
            #pragma unroll
            for (int r = 0; r < 4; ++r) {
                p0[r] = __builtin_amdgcn_exp2f(sc0[r]);
                p1[r] = __builtin_amdgcn_exp2f(sc1[r]);
            }
            union { uint32_t u[4]; bf16x8 v; } pa;
            pa.u[0] = cvtpk_bf2(p0[0], p0[1]); pa.u[1] = cvtpk_bf2(p0[2], p0[3]);
            pa.u[2] = cvtpk_bf2(p1[0], p1[1]); pa.u[3] = cvtpk_bf2(p1[2], p1[3]);
            __builtin_amdgcn_s_setprio(1);
            #pragma unroll
            for (int dj = 0; dj < 4; ++dj)
                O[set][dj] = mfma16(pa.v, vf[dj], O[set][dj]);
            Ol[set] = mfma16(pa.v, one8.v, Ol[set]);
            __builtin_amdgcn_s_setprio(0);
        }
    }

    // Ol[set][r] = sum over this wave's 32 keys for qrow set*16+quad*4+r
    // (replicated across l15). Cross-wk combine via sL; no shuffles needed.
    __syncthreads();  // all compute reads drained; safe to alias staging LDS
    u16* lO = sKV;    // [qrow128][dk64+2pad] bf16 = 8448 u16
    if (wk == 1) {
        #pragma unroll
        for (int set = 0; set < 4; ++set) {
            #pragma unroll
            for (int dj = 0; dj < 4; ++dj)
                #pragma unroll
                for (int r = 0; r < 4; ++r)
                    lO[(wq * 64 + set * 16 + quad * 4 + r) * 66 + dj * 16 + l15]
                        = f2bf(O[set][dj][r]);
            if (l15 == 0) {
                #pragma unroll
                for (int r = 0; r < 4; ++r)
                    sL[wq][set * 16 + quad * 4 + r] = Ol[set][r];
            }
        }
    }
    __syncthreads();
    if (wk == 0) {
        #pragma unroll
        for (int set = 0; set < 4; ++set) {
            float rl[4];
            #pragma unroll
            for (int r = 0; r < 4; ++r)
                rl[r] = 1.f / (Ol[set][r] + sL[wq][set * 16 + quad * 4 + r]);
            #pragma unroll
            for (int dj = 0; dj < 4; ++dj)
                #pragma unroll
                for (int r = 0; r < 4; ++r) {
                    float o = O[set][dj][r]
                        + bf2f(lO[(wq * 64 + set * 16 + quad * 4 + r) * 66 + dj * 16 + l15]);
                    ctx[(bS + q0 + set * 16 + quad * 4 + r) * D
                        + (size_t)h * 64 + dj * 16 + l15] = f2bf(o * rl[r]);
                }
        }
    }
}

// -------------------------------------------- layernorm over sum of parts
__global__ __launch_bounds__(256)
void k_layernorm2(const float* __restrict__ p0, const float* __restrict__ p1,
                  const float* __restrict__ resid, const float* __restrict__ bias,
                  const float* __restrict__ a, const float* __restrict__ g,
                  float* __restrict__ outf, u16* __restrict__ outb, int D)
{
    const int row = blockIdx.x, tid = threadIdx.x;
    const size_t base = (size_t)row * D;
    float v[3];
    float s = 0.f, sq = 0.f;
    #pragma unroll
    for (int i = 0; i < 3; ++i) {
        int c = tid + i * 256;
        float x = p0[base + c] + p1[base + c] + resid[base + c] + bias[c];
        v[i] = x; s += x; sq += x * x;
    }
    #pragma unroll
    for (int off = 32; off >= 1; off >>= 1) {
        s += __shfl_xor(s, off, 64);
        sq += __shfl_xor(sq, off, 64);
    }
    __shared__ float red[8];
    const int w = tid >> 6;
    if ((tid & 63) == 0) { red[w] = s; red[4 + w] = sq; }
    __syncthreads();
    s = red[0] + red[1] + red[2] + red[3];
    sq = red[4] + red[5] + red[6] + red[7];
    float mean = s / D;
    float var = fmaxf((sq - s * mean) / (D - 1), 0.f);
    float denom = sqrtf(var) + 1e-5f;
    float av = a[0], gv = g[0];
    #pragma unroll
    for (int i = 0; i < 3; ++i) {
        float y = av * ((v[i] - mean) / denom) + gv;
        if (outf) outf[base + tid + i * 256] = y;
        if (outb) outb[base + tid + i * 256] = f2bf(y);
    }
}

// ---------------------------------------------------------------- launch
extern "C" void kernel_launch(void* const* d_in, const int* in_sizes, int n_in,
                              void* d_out, int out_size, void* d_ws, size_t ws_size,
                              hipStream_t stream)
{
    constexpr int B = 2, S = 4096, D = 768, H = 12, F = 3072;
    constexpr int M = B * S;
    const float SCALE_Q = 1.4426950408889634f / 8.0f;  // log2(e)/sqrt(dk)
    const float* x  = (const float*)d_in[0];
    const float* wq = (const float*)d_in[1];
    const float* bq = (const float*)d_in[2];
    const float* wk = (const float*)d_in[3];
    const float* bk = (const float*)d_in[4];
    const float* wv = (const float*)d_in[5];
    const float* bv = (const float*)d_in[6];
    const float* wo = (const float*)d_in[7];
    const float* bo = (const float*)d_in[8];
    const float* w1 = (const float*)d_in[9];
    const float* b1 = (const float*)d_in[10];
    const float* w2 = (const float*)d_in[11];
    const float* b2 = (const float*)d_in[12];
    const float* a1 = (const float*)d_in[13];
    const float* g1 = (const float*)d_in[14];
    const float* a2 = (const float*)d_in[15];
    const float* g2 = (const float*)d_in[16];

    char* ws = (char*)d_ws;
    size_t off = 0;
    auto alloc = [&](size_t bytes) {
        void* p = ws + off;
        off = (off + bytes + 255) & ~(size_t)255;
        return p;
    };
    u16*   xb    = (u16*)alloc((size_t)M * D * 2);
    u16*   wqkvt = (u16*)alloc((size_t)3 * D * D * 2);
    u16*   wot   = (u16*)alloc((size_t)D * D * 2);
    u16*   w1t   = (u16*)alloc((size_t)D * F * 2);
    u16*   w2t   = (u16*)alloc((size_t)D * F * 2);
    u16*   qb    = (u16*)alloc((size_t)M * D * 2);
    u16*   kb    = (u16*)alloc((size_t)M * D * 2);
    u16*   vtg   = (u16*)alloc((size_t)M * D * 2);  // V transposed: [D][M]
    u16*   ctxb  = (u16*)alloc((size_t)M * D * 2);
    float* x1f   = (float*)alloc((size_t)M * D * 4);
    u16*   x1b   = (u16*)alloc((size_t)M * D * 2);
    u16*   ff1b  = (u16*)alloc((size_t)M * F * 2);

    float* p0a = (float*)qb;     // WO partial 0 over qb+kb   (dead after attn)
    float* p1a = (float*)ff1b;   // WO partial 1 over ff1b    (not yet live)
    float* p0b = (float*)qb;     // FF2 partial 0 over qb+kb
    float* p1b = (float*)vtg;    // FF2 partial 1 over vtg+ctxb (dead after WO)

    k_prep<<<6144 + 6912, 256, 0, stream>>>(x, xb, wq, wk, wv, wo, w1, w2,
                                            wqkvt, wot, w1t, w2t);

    k_gemm_qkv<<<dim3(M / 128, 3 * D / 128), 256, 0, stream>>>(
        xb, wqkvt, bq, bk, bv, qb, kb, vtg, M, D, SCALE_Q);

    k_attention<<<dim3(S / 128, B * H), 256, 0, stream>>>(qb, kb, vtg, ctxb, S, D, H, M);

    k_gemm_part<<<dim3(M / 128, D / 128, 2), 256, 0, stream>>>(
        ctxb, wot, p0a, p1a, M, D, D, D / 2);
    k_layernorm2<<<M, 256, 0, stream>>>(p0a, p1a, x, bo, a1, g1, x1f, x1b, D);

    k_gemm<true><<<dim3(M / 128, F / 128), 256, 0, stream>>>(
        x1b, w1t, b1, ff1b, M, F, D);
    k_gemm_part<<<dim3(M / 128, D / 128, 2), 256, 0, stream>>>(
        ff1b, w2t, p0b, p1b, M, D, F, F / 2);
    k_layernorm2<<<M, 256, 0, stream>>>(p0b, p1b, x1f, b2, a2, g2, (float*)d_out, nullptr, D);

    (void)in_sizes; (void)n_in; (void)out_size; (void)ws_size;
}